// Round 7
// baseline (244.055 us; speedup 1.0000x reference)
//
#include <hip/hip_runtime.h>
#include <hip/hip_fp16.h>

#define NNODES 100000
#define NEDGES 1600000

#define NBUCK  ((NNODES + 511) >> 9)      // 196 buckets of 512 nodes
#define BIN_EPT  16
#define BIN_TILE (256 * BIN_EPT)          // 4096 edges per bin block
#define NBINBLK  ((NEDGES + BIN_TILE - 1) / BIN_TILE)   // 391

static_assert(NNODES % 4 == 0, "fused kernel assumes exact node quads");

static constexpr float EPS = 1e-12f;

__device__ __forceinline__ float2 h2f(unsigned u) {
    __half2 h = __builtin_bit_cast(__half2, u);
    return __half22float2(h);
}

// ---------------- CSR build: bucketed counting sort ----------------

__global__ __launch_bounds__(256) void k_bhist(
    const int* __restrict__ dst, int* __restrict__ bcnt)
{
    __shared__ int cnt[NBUCK];
    for (int i = threadIdx.x; i < NBUCK; i += 256) cnt[i] = 0;
    __syncthreads();
    int base = blockIdx.x * BIN_TILE;
    #pragma unroll
    for (int i = 0; i < BIN_EPT; ++i) {
        int k = base + i * 256 + threadIdx.x;
        if (k < NEDGES) atomicAdd(&cnt[dst[k] >> 9], 1);
    }
    __syncthreads();
    for (int i = threadIdx.x; i < NBUCK; i += 256)
        if (cnt[i]) atomicAdd(&bcnt[i], cnt[i]);
}

__global__ __launch_bounds__(256) void k_bscan(
    const int* __restrict__ bcnt, int* __restrict__ bbase,
    int* __restrict__ bcur, int* __restrict__ rowptr)
{
    __shared__ int ls[256];
    int t = threadIdx.x;
    ls[t] = (t < NBUCK) ? bcnt[t] : 0;
    __syncthreads();
    for (int off = 1; off < 256; off <<= 1) {
        int u = (t >= off) ? ls[t - off] : 0;
        __syncthreads();
        ls[t] += u;
        __syncthreads();
    }
    if (t < NBUCK) {
        int b = (t == 0) ? 0 : ls[t - 1];
        bbase[t] = b;
        bcur[t]  = b;
    }
    if (t == 0) rowptr[NNODES] = NEDGES;
}

// bin edges into bucket-contiguous packed[] : (dst&511)<<17 | src
__global__ __launch_bounds__(256) void k_bin(
    const int* __restrict__ src, const int* __restrict__ dst,
    int* __restrict__ bcur, unsigned* __restrict__ packed)
{
    __shared__ int cnt[NBUCK];
    __shared__ int gb[NBUCK];
    for (int i = threadIdx.x; i < NBUCK; i += 256) cnt[i] = 0;
    __syncthreads();
    unsigned pk[BIN_EPT];
    int bk[BIN_EPT];
    int base = blockIdx.x * BIN_TILE;
    #pragma unroll
    for (int i = 0; i < BIN_EPT; ++i) {
        int k = base + i * 256 + threadIdx.x;
        bk[i] = -1;
        if (k < NEDGES) {
            int d = dst[k], s = src[k];
            bk[i] = d >> 9;
            pk[i] = ((unsigned)(d & 511) << 17) | (unsigned)s;
            atomicAdd(&cnt[bk[i]], 1);
        }
    }
    __syncthreads();
    for (int i = threadIdx.x; i < NBUCK; i += 256) {
        int c = cnt[i];
        gb[i] = c ? atomicAdd(&bcur[i], c) : 0;
        cnt[i] = 0;
    }
    __syncthreads();
    #pragma unroll
    for (int i = 0; i < BIN_EPT; ++i) {
        if (bk[i] >= 0) {
            int pos = gb[bk[i]] + atomicAdd(&cnt[bk[i]], 1);
            packed[pos] = pk[i];
        }
    }
}

// one block per bucket: local count -> local scan -> rowptr + esrc scatter
__global__ __launch_bounds__(512) void k_bucket(
    const unsigned* __restrict__ packed, const int* __restrict__ bbase,
    const int* __restrict__ bcnt, int* __restrict__ rowptr,
    int* __restrict__ esrc)
{
    __shared__ int cnt[512];
    __shared__ int loc[512];
    int b = blockIdx.x, t = threadIdx.x;
    int base = bbase[b];
    int n = bcnt[b];
    cnt[t] = 0;
    __syncthreads();
    for (int i = t; i < n; i += 512)
        atomicAdd(&cnt[packed[base + i] >> 17], 1);
    __syncthreads();
    int v = cnt[t];
    loc[t] = v;
    __syncthreads();
    for (int off = 1; off < 512; off <<= 1) {
        int u = (t >= off) ? loc[t - off] : 0;
        __syncthreads();
        loc[t] += u;
        __syncthreads();
    }
    int excl = loc[t] - v;
    int node = b * 512 + t;
    if (node < NNODES) rowptr[node] = base + excl;
    cnt[t] = base + excl;          // absolute cursor
    __syncthreads();
    for (int i = t; i < n; i += 512) {
        unsigned p = packed[base + i];
        int pos = atomicAdd(&cnt[p >> 17], 1);
        esrc[pos] = (int)(p & 0x1FFFFu);
    }
}

// ---------------- compute kernels ----------------

// hn16[N,32] = fp16 normalized relu(feat @ w1^T + b1); n[N] = max(||h||,eps)
__global__ __launch_bounds__(256) void k_lin1(
    const float* __restrict__ feat, const float* __restrict__ w1,
    const float* __restrict__ b1, __half* __restrict__ hn16,
    float* __restrict__ nrm)
{
    __shared__ float w1s[32][129];
    __shared__ float fs[8][128];
    for (int i = threadIdx.x; i < 32 * 128; i += 256)
        w1s[i >> 7][i & 127] = w1[i];
    int r = threadIdx.x >> 5, c = threadIdx.x & 31;
    float bc = b1[c];
    const int ntiles = (NNODES + 7) / 8;
    for (int tile = blockIdx.x; tile < ntiles; tile += gridDim.x) {
        int row0 = tile * 8;
        __syncthreads();
        for (int i = threadIdx.x; i < 8 * 128; i += 256) {
            int rr = row0 + (i >> 7);
            fs[i >> 7][i & 127] = (rr < NNODES) ? feat[rr * 128 + (i & 127)] : 0.f;
        }
        __syncthreads();
        int row = row0 + r;
        float acc = bc;
        #pragma unroll
        for (int k = 0; k < 128; ++k) acc += fs[r][k] * w1s[c][k];
        acc = fmaxf(acc, 0.f);
        float ss = acc * acc;
        #pragma unroll
        for (int off = 16; off > 0; off >>= 1) ss += __shfl_xor(ss, off);
        if (row < NNODES) {
            float n = fmaxf(sqrtf(ss), EPS);
            hn16[(size_t)row * 32 + c] = __float2half(acc / n);
            if (c == 0) nrm[row] = n;
        }
    }
}

// One wave per destination node; 8 groups of 8 lanes (8B fp16x4 per lane),
// 2-edge unroll => 16 independent gather chains per wave.
// Rows stored normalized: e = beta*dot(hn_s,hn_d); h_s = n_s*hn_s.
// Constant-shift softmax: e in [-|beta|,|beta|] => w = exp(e-|beta|), no max.
template <bool FUSED>
__global__ __launch_bounds__(256) void k_agnn(
    const __half* __restrict__ hn16, const float* __restrict__ nrm,
    const int* __restrict__ rowptr, const int* __restrict__ esrc,
    const float* __restrict__ betas, int layer,
    __half* __restrict__ hnout, float* __restrict__ nout,
    const float* __restrict__ w2, const float* __restrict__ b2,
    float* __restrict__ out)
{
    __shared__ float w2s[64][33];     // only used when FUSED
    __shared__ float4 osm[4][8];
    if (FUSED) {
        for (int i = threadIdx.x; i < 64 * 32; i += 256)
            w2s[i >> 5][i & 31] = w2[i];
    }
    int wid  = threadIdx.x >> 6;
    int node = blockIdx.x * 4 + wid;
    int lane = threadIdx.x & 63;
    int grp  = lane >> 3;            // 8 edge-groups
    int c4   = lane & 7;             // 8B slot (4 halves) within the 64B row

    const uint2* hrow = reinterpret_cast<const uint2*>(hn16);
    float beta = betas[layer];
    float absb = fabsf(beta);
    uint2 qd = hrow[(size_t)node * 8 + c4];
    float2 d01 = h2f(qd.x), d23 = h2f(qd.y);
    d01.x *= beta; d01.y *= beta; d23.x *= beta; d23.y *= beta;

    int start = rowptr[node], end = rowptr[node + 1];
    float den = 0.f;
    float4 acc = make_float4(0.f, 0.f, 0.f, 0.f);

    for (int i0 = start + grp; i0 < end; i0 += 16) {
        int i1 = i0 + 8;
        bool has1 = (i1 < end);
        int s0 = esrc[i0];
        int s1 = has1 ? esrc[i1] : s0;
        uint2 q0 = hrow[(size_t)s0 * 8 + c4];
        uint2 q1 = hrow[(size_t)s1 * 8 + c4];
        float n0 = nrm[s0];
        float n1 = nrm[s1];
        float2 a01 = h2f(q0.x), a23 = h2f(q0.y);
        float2 b01 = h2f(q1.x), b23 = h2f(q1.y);
        float p0 = a01.x * d01.x + a01.y * d01.y + a23.x * d23.x + a23.y * d23.y;
        float p1 = b01.x * d01.x + b01.y * d01.y + b23.x * d23.x + b23.y * d23.y;
        #pragma unroll
        for (int off = 4; off > 0; off >>= 1) {
            p0 += __shfl_xor(p0, off);
            p1 += __shfl_xor(p1, off);
        }
        float w0 = __expf(p0 - absb);                 // exp(e - |beta|)
        float w1 = has1 ? __expf(p1 - absb) : 0.f;
        float wn0 = w0 * n0, wn1 = w1 * n1;
        den += w0 + w1;
        acc.x += wn0 * a01.x + wn1 * b01.x;
        acc.y += wn0 * a01.y + wn1 * b01.y;
        acc.z += wn0 * a23.x + wn1 * b23.x;
        acc.w += wn0 * a23.y + wn1 * b23.y;
    }

    // merge the 8 groups (xor 8, 16, 32)
    #pragma unroll
    for (int D = 8; D <= 32; D <<= 1) {
        den   += __shfl_xor(den, D);
        acc.x += __shfl_xor(acc.x, D);
        acc.y += __shfl_xor(acc.y, D);
        acc.z += __shfl_xor(acc.z, D);
        acc.w += __shfl_xor(acc.w, D);
    }

    float inv = 1.f / fmaxf(den, EPS);
    float4 o;
    o.x = fmaxf(acc.x * inv, 0.f);
    o.y = fmaxf(acc.y * inv, 0.f);
    o.z = fmaxf(acc.z * inv, 0.f);
    o.w = fmaxf(acc.w * inv, 0.f);

    if (!FUSED) {
        if (grp == 0) {
            float ss = o.x * o.x + o.y * o.y + o.z * o.z + o.w * o.w;
            #pragma unroll
            for (int off = 4; off > 0; off >>= 1) ss += __shfl_xor(ss, off);
            float n = fmaxf(sqrtf(ss), EPS);
            float rn = 1.f / n;
            __half2 lo = __floats2half2_rn(o.x * rn, o.y * rn);
            __half2 hi = __floats2half2_rn(o.z * rn, o.w * rn);
            uint2 q;
            q.x = __builtin_bit_cast(unsigned, lo);
            q.y = __builtin_bit_cast(unsigned, hi);
            reinterpret_cast<uint2*>(hnout)[(size_t)node * 8 + c4] = q;
            if (c4 == 0) nout[node] = n;
        }
    } else {
        if (grp == 0) osm[wid][c4] = o;
        __syncthreads();   // exact grid: all threads arrive
        const float* op = reinterpret_cast<const float*>(osm[wid]);
        float a2 = b2[lane];
        #pragma unroll
        for (int k = 0; k < 32; ++k) a2 += op[k] * w2s[lane][k];
        float mx = a2;
        #pragma unroll
        for (int off = 32; off > 0; off >>= 1)
            mx = fmaxf(mx, __shfl_xor(mx, off));
        float ex = __expf(a2 - mx);
        float sm = ex;
        #pragma unroll
        for (int off = 32; off > 0; off >>= 1)
            sm += __shfl_xor(sm, off);
        out[(size_t)node * 64 + lane] = a2 - mx - __logf(sm);
    }
}

extern "C" void kernel_launch(void* const* d_in, const int* in_sizes, int n_in,
                              void* d_out, int out_size, void* d_ws, size_t ws_size,
                              hipStream_t stream)
{
    const float* feat  = (const float*)d_in[0];
    const int*   src   = (const int*)d_in[1];
    const int*   dst   = (const int*)d_in[2];
    const float* w1    = (const float*)d_in[3];
    const float* b1    = (const float*)d_in[4];
    const float* betas = (const float*)d_in[5];
    const float* w2    = (const float*)d_in[6];
    const float* b2    = (const float*)d_in[7];
    float* out = (float*)d_out;

    // workspace: hnA[N*32 f16]=6.4MB hnB[6.4MB] nA[N] nB[N] rowptr[N+1]
    // esrc[E]=6.4MB bcnt/bbase/bcur[196]. packed[E] aliases hnB (dead before
    // agnn L0 writes hnB).
    __half*   hnA    = (__half*)d_ws;
    __half*   hnB    = hnA + (size_t)NNODES * 32;
    float*    nA     = (float*)(hnB + (size_t)NNODES * 32);
    float*    nB     = nA + NNODES;
    int*      rowptr = (int*)(nB + NNODES);
    int*      esrc   = rowptr + NNODES + 1;
    int*      bcnt   = esrc + NEDGES;
    int*      bbase  = bcnt + NBUCK;
    int*      bcur   = bbase + NBUCK;
    unsigned* packed = (unsigned*)hnB;

    dim3 blk(256);

    // CSR build (built once, used by both layers)
    hipMemsetAsync(bcnt, 0, NBUCK * sizeof(int), stream);
    k_bhist<<<NBINBLK, blk, 0, stream>>>(dst, bcnt);
    k_bscan<<<1, blk, 0, stream>>>(bcnt, bbase, bcur, rowptr);
    k_bin<<<NBINBLK, blk, 0, stream>>>(src, dst, bcur, packed);
    k_bucket<<<NBUCK, 512, 0, stream>>>(packed, bbase, bcnt, rowptr, esrc);

    k_lin1<<<2048, blk, 0, stream>>>(feat, w1, b1, hnA, nA);

    int gWave = NNODES / 4;   // exact
    k_agnn<false><<<gWave, blk, 0, stream>>>(hnA, nA, rowptr, esrc, betas, 0,
                                             hnB, nB, nullptr, nullptr, nullptr);
    k_agnn<true><<<gWave, blk, 0, stream>>>(hnB, nB, rowptr, esrc, betas, 1,
                                            nullptr, nullptr, w2, b2, out);
}